// Round 1
// 114.687 us; speedup vs baseline: 1.0373x; 1.0373x over previous
//
#include <hip/hip_runtime.h>
#include <math.h>

// Problem constants (from reference): BS=64, NQ=300, NC=2, T=1280
constexpr int ROWS  = 19200;        // BS*NQ
constexpr int T     = 1280;
constexpr int COL4  = T / 4;        // 320 float4 per row
constexpr int TPR   = 64;           // one wave covers one row-chunk; 5 quads/thread
constexpr int QPT   = COL4 / TPR;   // 5
constexpr int BLOCK = 256;
constexpr int RPB   = BLOCK / TPR;  // 4 rows per block
constexpr int GRID  = ROWS / RPB;   // 4800 exactly

__device__ __forceinline__ float cost_one(float pcx, float pw,
                                          float px1, float px2,
                                          float base,   // cref - prob0
                                          float tcx, float tw) {
    // L1 span cost in (cx,w)
    float cspan = fabsf(pcx - tcx) + fabsf(pw - tw);
    // GIoU in (x1,x2)
    float tx1 = tcx - 0.5f * tw;
    float tx2 = tcx + 0.5f * tw;
    float lt = fmaxf(px1, tx1);
    float rb = fminf(px2, tx2);
    float inter = fmaxf(rb - lt, 0.0f);
    float uni = pw + tw - inter;                 // area_a + area_b - inter
    float iou = inter * __builtin_amdgcn_rcpf(uni);
    float left  = fminf(px1, tx1);
    float right = fmaxf(px2, tx2);
    float enclose = right - left;                // >= 0 by construction
    float giou = iou - (enclose - uni) * __builtin_amdgcn_rcpf(enclose);
    // total = cspan + (-giou) + (-prob0) + cref
    return cspan - giou + base;
}

__global__ __launch_bounds__(BLOCK) void cost_matrix_kernel(
        const float* __restrict__ logits,   // [ROWS,2]
        const float* __restrict__ spans,    // [ROWS,2]
        const float* __restrict__ tgt,      // [T,2]
        const float* __restrict__ ref,      // [ROWS,2]
        float* __restrict__ out) {          // [ROWS,T]
    int idx = blockIdx.x * BLOCK + threadIdx.x;   // < ROWS*TPR exactly
    int row = idx >> 6;          // TPR = 64 -> pure shift, wave == row-chunk
    int c   = idx & 63;

    // ---- per-row constants (amortized over 20 outputs) ----
    float2 lg = ((const float2*)logits)[row];
    // softmax[..,0] over 2 classes: 1/(1+exp(y-x)), exp via hw exp2
    float prob0 = __builtin_amdgcn_rcpf(
        1.0f + __builtin_amdgcn_exp2f((lg.y - lg.x) * 1.44269504088896f));

    float2 sp = ((const float2*)spans)[row];
    float pcx = sp.x, pw = sp.y;
    float px1 = pcx - 0.5f * pw;
    float px2 = pcx + 0.5f * pw;

    float2 rp = ((const float2*)ref)[row];
    float d0 = px1 - rp.x;
    float d1 = px2 - rp.y;
    float base = __builtin_amdgcn_sqrtf(d0 * d0 + d1 * d1) - prob0;  // cref - prob0

    const float4* tgt4 = (const float4*)tgt;
    // 32-bit index math is safe: ROWS*COL4 = 6.14M < 2^31
    float4* out4 = ((float4*)out) + row * COL4 + c;

    #pragma unroll
    for (int j = 0; j < QPT; ++j) {
        int q = c + j * TPR;             // quad index in [0,320)
        float4 t01 = tgt4[2 * q];
        float4 t23 = tgt4[2 * q + 1];
        float4 res;
        res.x = cost_one(pcx, pw, px1, px2, base, t01.x, t01.y);
        res.y = cost_one(pcx, pw, px1, px2, base, t01.z, t01.w);
        res.z = cost_one(pcx, pw, px1, px2, base, t23.x, t23.y);
        res.w = cost_one(pcx, pw, px1, px2, base, t23.z, t23.w);
        // plain streaming store: every wave store is one aligned contiguous
        // 1 KB segment inside a single row (5120 B row = 5 x 1 KB chunks)
        out4[j * TPR] = res;
    }
}

extern "C" void kernel_launch(void* const* d_in, const int* in_sizes, int n_in,
                              void* d_out, int out_size, void* d_ws, size_t ws_size,
                              hipStream_t stream) {
    const float* pred_logits = (const float*)d_in[0];
    const float* pred_spans  = (const float*)d_in[1];
    const float* tgt_spans   = (const float*)d_in[2];
    const float* ref_points  = (const float*)d_in[3];
    float* out = (float*)d_out;

    cost_matrix_kernel<<<GRID, BLOCK, 0, stream>>>(
        pred_logits, pred_spans, tgt_spans, ref_points, out);
}